// Round 1
// baseline (133.632 us; speedup 1.0000x reference)
//
#include <hip/hip_runtime.h>

// SJLT projection: y[b, idx[d,j]] += sign[d,j] * x[b,d]; y *= 0.5
// B=4096, D=16384, P=1024, C=4.
//
// Strategy: gather formulation. Precompute per output column p the list of
// (swizzled LDS index, sign) entries, grouped by d-chunk (8 chunks x 2048 d).
// Main kernel: 4 rows per block; stage x chunk in LDS as [d][4 rows] (16B
// granules, XOR-swizzled); each thread owns 4 output columns and gathers with
// ds_read_b128 (one read serves 4 rows).

#define BATCH     4096
#define ORIG_DIM  16384
#define PROJ_DIM  1024
#define CNZ       4
#define NCHUNK    8
#define CHUNK_D   2048      // ORIG_DIM / NCHUNK
#define S_PAD     48        // max entries per (chunk, p); Poisson(8) tail ~0
#define ROWS      4         // rows per block in main kernel

// workspace layout (bytes):
//   0      : int flag  (1 if rand_indices is int64)
//   64     : int cnt[NCHUNK][PROJ_DIM]                 (32768 B)
//   32832  : ushort entry[NCHUNK][S_PAD][PROJ_DIM]     (786432 B)
#define WS_CNT_OFF_I   16        // in ints
#define WS_ENTRY_OFF_B 32832
#define WS_NEEDED      (32832 + NCHUNK * S_PAD * PROJ_DIM * 2)

__global__ void k_init(const unsigned int* __restrict__ idx32,
                       int* __restrict__ ws_i) {
    int t = threadIdx.x;
    for (int i = t; i < NCHUNK * PROJ_DIM; i += 256) ws_i[WS_CNT_OFF_I + i] = 0;
    if (t < 64) {
        unsigned int v = idx32[2 * t + 1];
        unsigned long long b = __ballot(v == 0u);
        if (t == 0) ws_i[0] = (b == 0xFFFFFFFFFFFFFFFFull) ? 1 : 0;
    }
}

__global__ void k_fill(const unsigned int* __restrict__ idx32,
                       const int* __restrict__ signs,
                       int* __restrict__ ws_i,
                       unsigned short* __restrict__ entry) {
    int t = blockIdx.x * 256 + threadIdx.x;       // 0 .. 65535  == d*4 + j
    int flag64 = ws_i[0];
    unsigned int p = (flag64 ? idx32[2 * t] : idx32[t]) & (PROJ_DIM - 1);
    int d  = t >> 2;
    int sg = (signs[t] < 0) ? 1 : 0;
    int dl = d & (CHUNK_D - 1);
    int chunk = d >> 11;
    // swizzled granule index: LDS byte addr will be (sidx << 4)
    unsigned int sidx = ((unsigned int)dl & ~7u) |
                        (((unsigned int)dl & 7u) ^ (((unsigned int)dl >> 2) & 7u));
    unsigned short e = (unsigned short)((sidx << 1) | (unsigned int)sg);
    int slot = atomicAdd(&ws_i[WS_CNT_OFF_I + chunk * PROJ_DIM + (int)p], 1);
    if (slot < S_PAD)
        entry[(size_t)(chunk * S_PAD + slot) * PROJ_DIM + p] = e;
}

__launch_bounds__(256)
__global__ void k_main(const float* __restrict__ x,
                       const int* __restrict__ ws_i,
                       const unsigned short* __restrict__ entry,
                       float* __restrict__ y) {
    __shared__ float4 xs4[CHUNK_D];   // 32 KiB, [d][4 rows], XOR-swizzled granules
    const int tid = threadIdx.x;
    const int b0  = blockIdx.x * ROWS;
    const int l = tid & 63, w = tid >> 6;
    const int r = l & 3,  q = l >> 2;

    float4 acc[4] = {};  // acc[k] components .x..w = rows b0+0..3

    const float* xbase = x + (size_t)(b0 + r) * ORIG_DIM;

    for (int chunk = 0; chunk < NCHUNK; ++chunk) {
        // ---- stage 4 rows x 2048 d into LDS, swizzled ----
        const float* xrow = xbase + chunk * CHUNK_D;
        const unsigned int swz = ((unsigned int)(q & 7)) << 4;
        #pragma unroll
        for (int it = 0; it < 8; ++it) {
            int dl = w * 512 + it * 64 + q * 4;
            float4 v = *(const float4*)(xrow + dl);
            #pragma unroll
            for (int i = 0; i < 4; ++i) {
                unsigned int a = (((unsigned int)(dl + i) << 4) ^ swz)
                               | ((unsigned int)r << 2);
                float val = (i == 0) ? v.x : (i == 1) ? v.y : (i == 2) ? v.z : v.w;
                *(float*)((char*)xs4 + a) = val;
            }
        }
        __syncthreads();

        // ---- gather: each thread owns columns tid, tid+256, +512, +768 ----
        #pragma unroll
        for (int k = 0; k < 4; ++k) {
            int p = tid + 256 * k;
            int n = ws_i[WS_CNT_OFF_I + chunk * PROJ_DIM + p];
            n = n < S_PAD ? n : S_PAD;
            const unsigned short* ep =
                entry + (size_t)(chunk * S_PAD) * PROJ_DIM + p;
            for (int s = 0; s < n; ++s) {
                unsigned int e = ep[(size_t)s * PROJ_DIM];
                float4 v = *(const float4*)((const char*)xs4 +
                                            (((e >> 1)) << 4));
                float sg = (e & 1u) ? -1.0f : 1.0f;
                acc[k].x = fmaf(sg, v.x, acc[k].x);
                acc[k].y = fmaf(sg, v.y, acc[k].y);
                acc[k].z = fmaf(sg, v.z, acc[k].z);
                acc[k].w = fmaf(sg, v.w, acc[k].w);
            }
        }
        __syncthreads();
    }

    // ---- epilogue: y = acc * 1/sqrt(4) ----
    #pragma unroll
    for (int k = 0; k < 4; ++k) {
        int p = tid + 256 * k;
        y[(size_t)(b0 + 0) * PROJ_DIM + p] = acc[k].x * 0.5f;
        y[(size_t)(b0 + 1) * PROJ_DIM + p] = acc[k].y * 0.5f;
        y[(size_t)(b0 + 2) * PROJ_DIM + p] = acc[k].z * 0.5f;
        y[(size_t)(b0 + 3) * PROJ_DIM + p] = acc[k].w * 0.5f;
    }
}

// Fallback if workspace is too small: per-row LDS atomic scatter.
__global__ void k_fallback(const float* __restrict__ x,
                           const unsigned int* __restrict__ idx32,
                           const int* __restrict__ signs,
                           float* __restrict__ y) {
    __shared__ float ys[PROJ_DIM];
    __shared__ int sflag;
    int tid = threadIdx.x;
    int b = blockIdx.x;
    if (tid < 64) {
        unsigned int v = idx32[2 * tid + 1];
        unsigned long long bl = __ballot(v == 0u);
        if (tid == 0) sflag = (bl == 0xFFFFFFFFFFFFFFFFull) ? 1 : 0;
    }
    for (int i = tid; i < PROJ_DIM; i += 256) ys[i] = 0.0f;
    __syncthreads();
    int f = sflag;
    const float* xr = x + (size_t)b * ORIG_DIM;
    for (int d = tid; d < ORIG_DIM; d += 256) {
        float v = xr[d];
        #pragma unroll
        for (int j = 0; j < 4; ++j) {
            int t = d * 4 + j;
            unsigned int p = (f ? idx32[2 * t] : idx32[t]) & (PROJ_DIM - 1);
            atomicAdd(&ys[p], (signs[t] < 0) ? -v : v);
        }
    }
    __syncthreads();
    for (int i = tid; i < PROJ_DIM; i += 256)
        y[(size_t)b * PROJ_DIM + i] = ys[i] * 0.5f;
}

extern "C" void kernel_launch(void* const* d_in, const int* in_sizes, int n_in,
                              void* d_out, int out_size, void* d_ws, size_t ws_size,
                              hipStream_t stream) {
    const float*        x     = (const float*)d_in[0];
    const unsigned int* idx32 = (const unsigned int*)d_in[1];
    const int*          signs = (const int*)d_in[2];
    float*              y     = (float*)d_out;

    if (ws_size >= (size_t)WS_NEEDED) {
        int* ws_i = (int*)d_ws;
        unsigned short* entry = (unsigned short*)((char*)d_ws + WS_ENTRY_OFF_B);
        k_init<<<1, 256, 0, stream>>>(idx32, ws_i);
        k_fill<<<(ORIG_DIM * CNZ) / 256, 256, 0, stream>>>(idx32, signs, ws_i, entry);
        k_main<<<BATCH / ROWS, 256, 0, stream>>>(x, ws_i, entry, y);
    } else {
        k_fallback<<<BATCH, 256, 0, stream>>>(x, idx32, signs, y);
    }
}

// Round 2
// 102.347 us; speedup vs baseline: 1.3057x; 1.3057x over previous
//
#include <hip/hip_runtime.h>

// SJLT projection: y[b, idx[d,j]] += sign[d,j] * x[b,d]; y *= 0.5
// B=4096, D=16384, P=1024, C=4.
//
// Gather formulation, latency-optimized:
//  - entry lists per (chunk=1024 d's, output col p): head of exactly 8 ushort
//    entries (dummy-padded to a zero LDS granule) loaded as ONE dwordx4,
//    rare overflow (n>8) in a tail array.
//  - main kernel: 4 rows/block, double-buffered LDS chunk staging with
//    register prefetch issued before the barrier (loads in flight during
//    gather), in-register 4x4 transpose so staging is 4x ds_write_b128,
//    XOR-swizzled granules (bank-balanced writes).

#define BATCH     4096
#define ORIG_DIM  16384
#define PROJ_DIM  1024
#define NCHUNK    16
#define CHUNK_D   1024      // ORIG_DIM / NCHUNK
#define ROWS      4
#define HEAD_CAP  8
#define TAIL_CAP  16        // entries 8..23; P(n>24 | lambda=4) ~ 1e-13
#define DUMMY_E   ((unsigned short)(1024u << 1))   // zero-granule, +sign

// ws layout (bytes):
//   0      : int flag (1 if rand_indices is int64)
//   64     : int cnt[NCHUNK*PROJ_DIM]                  (65536 B)
//   65600  : ushort head[NCHUNK*PROJ_DIM*HEAD_CAP]     (262144 B)
//   327744 : ushort tail[NCHUNK*PROJ_DIM*TAIL_CAP]     (524288 B)
#define WS_CNT_I    16
#define WS_HEAD_B   65600
#define WS_TAIL_B   327744
#define WS_NEEDED   (327744 + 524288)

typedef float  f32x2 __attribute__((ext_vector_type(2)));
typedef unsigned short u16x8 __attribute__((ext_vector_type(8)));

__global__ void k_init(const unsigned int* __restrict__ idx32,
                       int* __restrict__ ws_i,
                       unsigned short* __restrict__ head) {
    int t = blockIdx.x * 256 + threadIdx.x;     // 16384 threads
    ws_i[WS_CNT_I + t] = 0;
    u16x8 d8 = { DUMMY_E, DUMMY_E, DUMMY_E, DUMMY_E,
                 DUMMY_E, DUMMY_E, DUMMY_E, DUMMY_E };
    *(u16x8*)(head + (size_t)t * HEAD_CAP) = d8;
    if (blockIdx.x == 0 && threadIdx.x < 64) {
        unsigned int v = idx32[2 * threadIdx.x + 1];
        unsigned long long b = __ballot(v == 0u);
        if (threadIdx.x == 0) ws_i[0] = (b == 0xFFFFFFFFFFFFFFFFull) ? 1 : 0;
    }
}

__global__ void k_fill(const unsigned int* __restrict__ idx32,
                       const int* __restrict__ signs,
                       int* __restrict__ ws_i,
                       unsigned short* __restrict__ head,
                       unsigned short* __restrict__ tail) {
    int t = blockIdx.x * 256 + threadIdx.x;     // 0..65535 == d*4 + j
    int flag64 = ws_i[0];
    unsigned int p = (flag64 ? idx32[2 * t] : idx32[t]) & (PROJ_DIM - 1);
    int d  = t >> 2;
    int sg = (signs[t] < 0) ? 1 : 0;
    int chunk = d >> 10;
    int dl = d & (CHUNK_D - 1);
    unsigned int slot = (unsigned int)dl ^ (((unsigned int)dl >> 3) & 7u);
    unsigned short e = (unsigned short)((slot << 1) | (unsigned int)sg);
    int base = chunk * PROJ_DIM + (int)p;
    int pos = atomicAdd(&ws_i[WS_CNT_I + base], 1);
    if (pos < HEAD_CAP)
        head[(size_t)base * HEAD_CAP + pos] = e;
    else if (pos < HEAD_CAP + TAIL_CAP)
        tail[(size_t)base * TAIL_CAP + (pos - HEAD_CAP)] = e;
}

#define PROCK(E, A0, A1) { \
    unsigned int _e = (unsigned int)(E); \
    float4 _g = xsb[_e >> 1]; \
    float _sg = (_e & 1u) ? -1.0f : 1.0f; \
    f32x2 _sv = { _sg, _sg }; \
    f32x2 _lo = { _g.x, _g.y }; \
    f32x2 _hi = { _g.z, _g.w }; \
    A0 = __builtin_elementwise_fma(_sv, _lo, A0); \
    A1 = __builtin_elementwise_fma(_sv, _hi, A1); }

__launch_bounds__(256)
__global__ void k_main(const float* __restrict__ x,
                       const int* __restrict__ cnt,
                       const unsigned short* __restrict__ head,
                       const unsigned short* __restrict__ tail,
                       float* __restrict__ y) {
    __shared__ float4 xs[2][CHUNK_D + 1];   // 2 x 16.4 KiB; slot CHUNK_D = zeros
    const int tid = threadIdx.x;
    const int b0  = blockIdx.x * ROWS;
    const float* xp = x + (size_t)b0 * ORIG_DIM + tid * 4;

    if (tid == 0) {
        xs[0][CHUNK_D] = float4{0.f, 0.f, 0.f, 0.f};
        xs[1][CHUNK_D] = float4{0.f, 0.f, 0.f, 0.f};
    }

    // prefetch chunk 0 into regs (one float4 per row)
    float4 v0 = *(const float4*)(xp + 0 * ORIG_DIM);
    float4 v1 = *(const float4*)(xp + 1 * ORIG_DIM);
    float4 v2 = *(const float4*)(xp + 2 * ORIG_DIM);
    float4 v3 = *(const float4*)(xp + 3 * ORIG_DIM);

    f32x2 accA[4], accB[4];
    #pragma unroll
    for (int k = 0; k < 4; ++k) { accA[k] = f32x2{0.f, 0.f}; accB[k] = f32x2{0.f, 0.f}; }

    for (int ch = 0; ch < NCHUNK; ++ch) {
        float4* xsb = xs[ch & 1];
        // ---- stage: in-register transpose, 4x ds_write_b128, swizzled ----
        #pragma unroll
        for (int i = 0; i < 4; ++i) {
            int dl = tid * 4 + i;
            int slot = dl ^ ((dl >> 3) & 7);
            float a = (i == 0) ? v0.x : (i == 1) ? v0.y : (i == 2) ? v0.z : v0.w;
            float b = (i == 0) ? v1.x : (i == 1) ? v1.y : (i == 2) ? v1.z : v1.w;
            float c = (i == 0) ? v2.x : (i == 1) ? v2.y : (i == 2) ? v2.z : v2.w;
            float d = (i == 0) ? v3.x : (i == 1) ? v3.y : (i == 2) ? v3.z : v3.w;
            xsb[slot] = float4{a, b, c, d};
        }
        // ---- issue next chunk's global loads (in flight across barrier) ----
        if (ch + 1 < NCHUNK) {
            const float* xq = xp + (size_t)(ch + 1) * CHUNK_D;
            v0 = *(const float4*)(xq + 0 * ORIG_DIM);
            v1 = *(const float4*)(xq + 1 * ORIG_DIM);
            v2 = *(const float4*)(xq + 2 * ORIG_DIM);
            v3 = *(const float4*)(xq + 3 * ORIG_DIM);
        }
        __syncthreads();

        // ---- gather: batch count+head loads, then branch-free head-8 ----
        const int base0 = ch * PROJ_DIM + tid;
        int   n[4];
        u16x8 h[4];
        #pragma unroll
        for (int k = 0; k < 4; ++k) {
            int base = base0 + 256 * k;
            n[k] = cnt[base];
            h[k] = *(const u16x8*)(head + ((size_t)base << 3));
        }
        #pragma unroll
        for (int k = 0; k < 4; ++k) {
            PROCK(h[k][0], accA[k], accB[k]);
            PROCK(h[k][1], accA[k], accB[k]);
            PROCK(h[k][2], accA[k], accB[k]);
            PROCK(h[k][3], accA[k], accB[k]);
            PROCK(h[k][4], accA[k], accB[k]);
            PROCK(h[k][5], accA[k], accB[k]);
            PROCK(h[k][6], accA[k], accB[k]);
            PROCK(h[k][7], accA[k], accB[k]);
            if (n[k] > HEAD_CAP) {
                int base = base0 + 256 * k;
                int e_end = n[k] < HEAD_CAP + TAIL_CAP ? n[k] : HEAD_CAP + TAIL_CAP;
                const unsigned short* tp = tail + ((size_t)base << 4);
                for (int s = HEAD_CAP; s < e_end; ++s)
                    PROCK(tp[s - HEAD_CAP], accA[k], accB[k]);
            }
        }
        __syncthreads();
    }

    // ---- epilogue: y = acc * 1/sqrt(4) ----
    #pragma unroll
    for (int k = 0; k < 4; ++k) {
        int p = tid + 256 * k;
        float* yb = y + (size_t)b0 * PROJ_DIM + p;
        yb[0 * PROJ_DIM] = accA[k][0] * 0.5f;
        yb[1 * PROJ_DIM] = accA[k][1] * 0.5f;
        yb[2 * PROJ_DIM] = accB[k][0] * 0.5f;
        yb[3 * PROJ_DIM] = accB[k][1] * 0.5f;
    }
}

// Fallback if workspace is too small: per-row LDS atomic scatter.
__global__ void k_fallback(const float* __restrict__ x,
                           const unsigned int* __restrict__ idx32,
                           const int* __restrict__ signs,
                           float* __restrict__ y) {
    __shared__ float ys[PROJ_DIM];
    __shared__ int sflag;
    int tid = threadIdx.x;
    int b = blockIdx.x;
    if (tid < 64) {
        unsigned int v = idx32[2 * tid + 1];
        unsigned long long bl = __ballot(v == 0u);
        if (tid == 0) sflag = (bl == 0xFFFFFFFFFFFFFFFFull) ? 1 : 0;
    }
    for (int i = tid; i < PROJ_DIM; i += 256) ys[i] = 0.0f;
    __syncthreads();
    int f = sflag;
    const float* xr = x + (size_t)b * ORIG_DIM;
    for (int d = tid; d < ORIG_DIM; d += 256) {
        float v = xr[d];
        #pragma unroll
        for (int j = 0; j < 4; ++j) {
            int t = d * 4 + j;
            unsigned int p = (f ? idx32[2 * t] : idx32[t]) & (PROJ_DIM - 1);
            atomicAdd(&ys[p], (signs[t] < 0) ? -v : v);
        }
    }
    __syncthreads();
    for (int i = tid; i < PROJ_DIM; i += 256)
        y[(size_t)b * PROJ_DIM + i] = ys[i] * 0.5f;
}

extern "C" void kernel_launch(void* const* d_in, const int* in_sizes, int n_in,
                              void* d_out, int out_size, void* d_ws, size_t ws_size,
                              hipStream_t stream) {
    const float*        x     = (const float*)d_in[0];
    const unsigned int* idx32 = (const unsigned int*)d_in[1];
    const int*          signs = (const int*)d_in[2];
    float*              y     = (float*)d_out;

    if (ws_size >= (size_t)WS_NEEDED) {
        int* ws_i = (int*)d_ws;
        unsigned short* head = (unsigned short*)((char*)d_ws + WS_HEAD_B);
        unsigned short* tail = (unsigned short*)((char*)d_ws + WS_TAIL_B);
        k_init<<<64, 256, 0, stream>>>(idx32, ws_i, head);
        k_fill<<<(ORIG_DIM * 4) / 256, 256, 0, stream>>>(idx32, signs, ws_i, head, tail);
        k_main<<<BATCH / ROWS, 256, 0, stream>>>(x, ws_i + WS_CNT_I, head, tail, y);
    } else {
        k_fallback<<<BATCH, 256, 0, stream>>>(x, idx32, signs, y);
    }
}